// Round 6
// baseline (405.080 us; speedup 1.0000x reference)
//
#include <hip/hip_runtime.h>
#include <hip/hip_bf16.h>
#include <math.h>

// B=64, H=1024, I=512. out[b,o] = tanh( dot(x[b,:],W_ih[o,:]) + b_ih[o]
//                                       + softmax_h(W_hh[o,:]/tau + g[b,o,:]) . h_prev[b,:] )
//
// R6 = MEASUREMENT ROUND. R1 kernel (known 362 us total) launched TWICE:
// dur_us - 362 = exact kernel slice, since dur_us includes ~245-320 us of
// harness restore/poison (evidence: R0==R1==~363 despite different kernels;
// our kernel absent from top-5 dispatches so per-dispatch < 157 us; R5's
// worse access pattern added +40 -> kernel-controlled slice is 40-120 us vs
// 43 us HBM floor for the 268 MB gumbel stream).
// Second launch is idempotent (recomputes identical output from unchanged
// inputs) -> same work every call, graph-capture safe, validation unaffected.

constexpr int B_ = 64;
constexpr int H_ = 1024;
constexpr int I_ = 512;

__global__ __launch_bounds__(256) void reservoir_fused_kernel(
    const float* __restrict__ x_t,         // (B, I)
    const float* __restrict__ h_prev,      // (B, H)
    const float* __restrict__ W_ih,        // (H, I)
    const float* __restrict__ b_ih,        // (H,)
    const float* __restrict__ W_hh,        // (H, H)
    const float* __restrict__ temperature, // scalar
    const float* __restrict__ gumbel,      // (B, H, H)
    float* __restrict__ out)               // (B, H)
{
    const int gtid = blockIdx.x * blockDim.x + threadIdx.x;
    const int wave = gtid >> 6;
    const int lane = gtid & 63;
    // o fastest: consecutive waves stream consecutive 4 KB gumbel rows, and
    // all 4 waves of a block share b (h_prev row stays hot in L1).
    const int b = wave >> 10;
    const int o = wave & (H_ - 1);

    const float tau = fmaxf(temperature[0], 1e-3f);
    const float inv_tau = 1.0f / tau;

    // ---- input contribution partial: dot(x[b,:], W_ih[o,:]), 8 elems/lane ----
    float ic = 0.0f;
    {
        const float4* x4 = reinterpret_cast<const float4*>(x_t + (size_t)b * I_);
        const float4* w4 = reinterpret_cast<const float4*>(W_ih + (size_t)o * I_);
#pragma unroll
        for (int c = 0; c < I_ / 256; ++c) {   // 2 iters
            float4 xv = x4[c * 64 + lane];
            float4 wv = w4[c * 64 + lane];
            ic = fmaf(xv.x, wv.x, ic);
            ic = fmaf(xv.y, wv.y, ic);
            ic = fmaf(xv.z, wv.z, ic);
            ic = fmaf(xv.w, wv.w, ic);
        }
    }

    // ---- streaming exp-sum and weighted sum over the 1024-wide row ----
    float s = 0.0f, t = 0.0f;
    {
        const float4* g4 = reinterpret_cast<const float4*>(gumbel + ((size_t)b * H_ + o) * H_);
        const float4* w4 = reinterpret_cast<const float4*>(W_hh + (size_t)o * H_);
        const float4* h4 = reinterpret_cast<const float4*>(h_prev + (size_t)b * H_);
#pragma unroll
        for (int c = 0; c < 4; ++c) {
            float4 g = g4[c * 64 + lane];
            float4 w = w4[c * 64 + lane];
            float4 h = h4[c * 64 + lane];
            float e0 = __expf(fmaf(w.x, inv_tau, g.x));
            float e1 = __expf(fmaf(w.y, inv_tau, g.y));
            float e2 = __expf(fmaf(w.z, inv_tau, g.z));
            float e3 = __expf(fmaf(w.w, inv_tau, g.w));
            s += (e0 + e1) + (e2 + e3);
            t = fmaf(e0, h.x, t);
            t = fmaf(e1, h.y, t);
            t = fmaf(e2, h.z, t);
            t = fmaf(e3, h.w, t);
        }
    }

    // ---- wave-wide sums: s, t, ic together (interleaved for ILP) ----
#pragma unroll
    for (int off = 32; off > 0; off >>= 1) {
        s  += __shfl_xor(s,  off, 64);
        t  += __shfl_xor(t,  off, 64);
        ic += __shfl_xor(ic, off, 64);
    }

    if (lane == 0) {
        float res = tanhf(ic + b_ih[o] + t / s);
        out[(size_t)b * H_ + o] = res;
    }
}

extern "C" void kernel_launch(void* const* d_in, const int* in_sizes, int n_in,
                              void* d_out, int out_size, void* d_ws, size_t ws_size,
                              hipStream_t stream) {
    const float* x_t    = (const float*)d_in[0];
    const float* h_prev = (const float*)d_in[1];
    const float* W_ih   = (const float*)d_in[2];
    const float* b_ih   = (const float*)d_in[3];
    const float* W_hh   = (const float*)d_in[4];
    const float* temp   = (const float*)d_in[5];
    const float* gum    = (const float*)d_in[6];
    float* out = (float*)d_out;

    const int total_waves = B_ * H_;      // 65536 rows
    const int blocks = total_waves / 4;   // 256 threads = 4 waves per block

    // Launch TWICE: dur_us(this round) - dur_us(R1) isolates one kernel's
    // exact duration from the harness-dominated timed window. Idempotent.
    reservoir_fused_kernel<<<blocks, 256, 0, stream>>>(
        x_t, h_prev, W_ih, b_ih, W_hh, temp, gum, out);
    reservoir_fused_kernel<<<blocks, 256, 0, stream>>>(
        x_t, h_prev, W_ih, b_ih, W_hh, temp, gum, out);
}

// Round 7
// 363.322 us; speedup vs baseline: 1.1149x; 1.1149x over previous
//
#include <hip/hip_runtime.h>
#include <hip/hip_bf16.h>
#include <math.h>

// B=64, H=1024, I=512. out[b,o] = tanh( dot(x[b,:],W_ih[o,:]) + b_ih[o]
//                                       + softmax_h(W_hh[o,:]/tau + g[b,o,:]) . h_prev[b,:] )
//
// FINAL (R7 = R1 restored after R6's double-launch measurement round):
// one wave per (b,o) row, fully coalesced float4 loads, streaming softmax
// without the max pass (logits bounded: gumbel clamp u in [1e-8,1-1e-8] ->
// g in [-2.92, 18.42], W_hh/tau ~ +-0.1 -> exp < 1.2e8, row sum < 1.2e11,
// no overflow; absmax 2e-3 vs 2e-2 threshold).
//
// ROOFLINE EVIDENCE (R6): double-launch dur 405.1 vs single 362.4 us ->
// kernel slice = 42.7 us. Unavoidable HBM traffic = 268.4 MB gumbel (read
// once) + ~6 MB cached weights = ~275 MB; at the 6.7 TB/s this box sustains
// (harness fills), floor = ~41 us. Kernel is at ~96% of the memory-bound
// limit. Remaining ~320 us of dur_us is the harness restore/poison window
// (1.07 GB fill alone = ~160 us in every profile), outside kernel control.

constexpr int B_ = 64;
constexpr int H_ = 1024;
constexpr int I_ = 512;

__global__ __launch_bounds__(256) void reservoir_fused_kernel(
    const float* __restrict__ x_t,         // (B, I)
    const float* __restrict__ h_prev,      // (B, H)
    const float* __restrict__ W_ih,        // (H, I)
    const float* __restrict__ b_ih,        // (H,)
    const float* __restrict__ W_hh,        // (H, H)
    const float* __restrict__ temperature, // scalar
    const float* __restrict__ gumbel,      // (B, H, H)
    float* __restrict__ out)               // (B, H)
{
    const int gtid = blockIdx.x * blockDim.x + threadIdx.x;
    const int wave = gtid >> 6;
    const int lane = gtid & 63;
    // o fastest: consecutive waves stream consecutive 4 KB gumbel rows, and
    // all 4 waves of a block share b (h_prev row stays hot in L1).
    const int b = wave >> 10;
    const int o = wave & (H_ - 1);

    const float tau = fmaxf(temperature[0], 1e-3f);
    const float inv_tau = 1.0f / tau;

    // ---- input contribution partial: dot(x[b,:], W_ih[o,:]), 8 elems/lane ----
    float ic = 0.0f;
    {
        const float4* x4 = reinterpret_cast<const float4*>(x_t + (size_t)b * I_);
        const float4* w4 = reinterpret_cast<const float4*>(W_ih + (size_t)o * I_);
#pragma unroll
        for (int c = 0; c < I_ / 256; ++c) {   // 2 iters
            float4 xv = x4[c * 64 + lane];
            float4 wv = w4[c * 64 + lane];
            ic = fmaf(xv.x, wv.x, ic);
            ic = fmaf(xv.y, wv.y, ic);
            ic = fmaf(xv.z, wv.z, ic);
            ic = fmaf(xv.w, wv.w, ic);
        }
    }

    // ---- streaming exp-sum and weighted sum over the 1024-wide row ----
    float s = 0.0f, t = 0.0f;
    {
        const float4* g4 = reinterpret_cast<const float4*>(gumbel + ((size_t)b * H_ + o) * H_);
        const float4* w4 = reinterpret_cast<const float4*>(W_hh + (size_t)o * H_);
        const float4* h4 = reinterpret_cast<const float4*>(h_prev + (size_t)b * H_);
#pragma unroll
        for (int c = 0; c < 4; ++c) {
            float4 g = g4[c * 64 + lane];
            float4 w = w4[c * 64 + lane];
            float4 h = h4[c * 64 + lane];
            float e0 = __expf(fmaf(w.x, inv_tau, g.x));
            float e1 = __expf(fmaf(w.y, inv_tau, g.y));
            float e2 = __expf(fmaf(w.z, inv_tau, g.z));
            float e3 = __expf(fmaf(w.w, inv_tau, g.w));
            s += (e0 + e1) + (e2 + e3);
            t = fmaf(e0, h.x, t);
            t = fmaf(e1, h.y, t);
            t = fmaf(e2, h.z, t);
            t = fmaf(e3, h.w, t);
        }
    }

    // ---- wave-wide sums: s, t, ic together (interleaved for ILP) ----
#pragma unroll
    for (int off = 32; off > 0; off >>= 1) {
        s  += __shfl_xor(s,  off, 64);
        t  += __shfl_xor(t,  off, 64);
        ic += __shfl_xor(ic, off, 64);
    }

    if (lane == 0) {
        float res = tanhf(ic + b_ih[o] + t / s);
        out[(size_t)b * H_ + o] = res;
    }
}

extern "C" void kernel_launch(void* const* d_in, const int* in_sizes, int n_in,
                              void* d_out, int out_size, void* d_ws, size_t ws_size,
                              hipStream_t stream) {
    const float* x_t    = (const float*)d_in[0];
    const float* h_prev = (const float*)d_in[1];
    const float* W_ih   = (const float*)d_in[2];
    const float* b_ih   = (const float*)d_in[3];
    const float* W_hh   = (const float*)d_in[4];
    const float* temp   = (const float*)d_in[5];
    const float* gum    = (const float*)d_in[6];
    float* out = (float*)d_out;

    const int total_waves = B_ * H_;      // 65536 rows
    const int blocks = total_waves / 4;   // 256 threads = 4 waves per block
    reservoir_fused_kernel<<<blocks, 256, 0, stream>>>(
        x_t, h_prev, W_ih, b_ih, W_hh, temp, gum, out);
}